// Round 3
// baseline (268.066 us; speedup 1.0000x reference)
//
#include <hip/hip_runtime.h>
#include <hip/hip_bf16.h>
#include <cstdint>
#include <cstddef>

typedef __hip_bfloat16 bf16;
typedef short bf16x8 __attribute__((ext_vector_type(8)));
typedef float f32x4 __attribute__((ext_vector_type(4)));
typedef int i32x4 __attribute__((ext_vector_type(4)));

#define MFMA16(a, b, c) __builtin_amdgcn_mfma_f32_16x16x32_bf16((a), (b), (c), 0, 0, 0)

// ---------------------------------------------------------------- converts
__global__ void cvt_f32_bf16(const float* __restrict__ in, bf16* __restrict__ out, int n4)
{
    int i = blockIdx.x * blockDim.x + threadIdx.x;
    if (i >= n4) return;
    float4 v = *reinterpret_cast<const float4*>(in + (size_t)i * 4);
    __align__(8) bf16 tmp[4];
    tmp[0] = __float2bfloat16(v.x);
    tmp[1] = __float2bfloat16(v.y);
    tmp[2] = __float2bfloat16(v.z);
    tmp[3] = __float2bfloat16(v.w);
    *reinterpret_cast<short4*>(out + (size_t)i * 4) = *reinterpret_cast<short4*>(tmp);
}

// ---------------------------------------------------------------- rope table
// tab[pos][f] = (cos, sin) of pos * 10000^(-f/32), pos in [0,2048), f in [0,32)
__global__ void rope_table_kernel(float2* __restrict__ tab)
{
    int i = blockIdx.x * blockDim.x + threadIdx.x;   // 65536
    int pos = i >> 5, f = i & 31;
    float inv = powf(10000.f, -(float)f * (1.f / 32.f));
    float ang = (float)pos * inv;
    tab[i] = make_float2(cosf(ang), sinf(ang));
}

// ---------------------------------------------------------------- rope apply (in-place on q,k cols of qkv buffer)
__global__ void rope_apply_kernel(bf16* __restrict__ qkv, const float2* __restrict__ tab)
{
    int idx = blockIdx.x * blockDim.x + threadIdx.x;   // 1,048,576 total; 8 bf16 each
    int row = idx >> 8;          // 4096 rows, 256 chunks of 8 over cols [0,2048)
    int cc  = (idx & 255) * 8;
    int pos = row & 2047;
    int hd  = cc & 63;
    bf16* p = qkv + (size_t)row * 3072 + cc;
    i32x4 v = *reinterpret_cast<const i32x4*>(p);
    bf16* e = reinterpret_cast<bf16*>(&v);
    const float2* tb = tab + pos * 32 + (hd >> 1);
#pragma unroll
    for (int pp = 0; pp < 4; ++pp) {
        float2 cs = tb[pp];
        float x1 = __bfloat162float(e[2 * pp]);
        float x2 = __bfloat162float(e[2 * pp + 1]);
        e[2 * pp]     = __float2bfloat16(x1 * cs.x - x2 * cs.y);
        e[2 * pp + 1] = __float2bfloat16(x2 * cs.x + x1 * cs.y);
    }
    *reinterpret_cast<i32x4*>(p) = v;
}

// ---------------------------------------------------------------- GEMM  C[M,N] = A[M,K] @ BT[N,K]^T + bias
__device__ inline void store_out(float* p, float v) { *p = v; }
__device__ inline void store_out(bf16* p, float v) { *p = __float2bfloat16(v); }

template <typename OutT>
__global__ void gemm_bt_kernel(const bf16* __restrict__ A, const bf16* __restrict__ BT,
                               const float* __restrict__ bias, OutT* __restrict__ C,
                               int M, int N, int K)
{
    constexpr int BM = 128, BN = 128, BK = 32, LDT = BK + 8;   // +8 bf16 pad: 2-way banks
    __shared__ __align__(16) bf16 Al[BM * LDT];
    __shared__ __align__(16) bf16 Bl[BN * LDT];

    const int tid = threadIdx.x;
    const int l = tid & 63;
    const int w = tid >> 6;
    const int wr = w >> 1, wc = w & 1;          // 2x2 wave grid, 64x64 per wave
    const int lane15 = l & 15, lhi = l >> 4;
    const int row0 = blockIdx.x * BM, col0 = blockIdx.y * BN;

    // staging: 512 chunks of 8 bf16; chunk c: row=c>>2, col8=(c&3)*8
    const int c0 = tid, c1 = tid + 256;
    const bf16* Ag0 = A + (size_t)(row0 + (c0 >> 2)) * K + (c0 & 3) * 8;
    const bf16* Ag1 = A + (size_t)(row0 + (c1 >> 2)) * K + (c1 & 3) * 8;
    const bf16* Bg0 = BT + (size_t)(col0 + (c0 >> 2)) * K + (c0 & 3) * 8;
    const bf16* Bg1 = BT + (size_t)(col0 + (c1 >> 2)) * K + (c1 & 3) * 8;
    bf16* sA0 = &Al[(c0 >> 2) * LDT + (c0 & 3) * 8];
    bf16* sA1 = &Al[(c1 >> 2) * LDT + (c1 & 3) * 8];
    bf16* sB0 = &Bl[(c0 >> 2) * LDT + (c0 & 3) * 8];
    bf16* sB1 = &Bl[(c1 >> 2) * LDT + (c1 & 3) * 8];

    f32x4 acc[4][4] = {};

    i32x4 ra0 = *reinterpret_cast<const i32x4*>(Ag0);
    i32x4 ra1 = *reinterpret_cast<const i32x4*>(Ag1);
    i32x4 rb0 = *reinterpret_cast<const i32x4*>(Bg0);
    i32x4 rb1 = *reinterpret_cast<const i32x4*>(Bg1);

    for (int k0 = 0; k0 < K; k0 += BK) {
        __syncthreads();                                    // all frag reads of prev tile done
        *reinterpret_cast<i32x4*>(sA0) = ra0;
        *reinterpret_cast<i32x4*>(sA1) = ra1;
        *reinterpret_cast<i32x4*>(sB0) = rb0;
        *reinterpret_cast<i32x4*>(sB1) = rb1;
        __syncthreads();
        if (k0 + BK < K) {                                  // prefetch next tile into regs
            ra0 = *reinterpret_cast<const i32x4*>(Ag0 + k0 + BK);
            ra1 = *reinterpret_cast<const i32x4*>(Ag1 + k0 + BK);
            rb0 = *reinterpret_cast<const i32x4*>(Bg0 + k0 + BK);
            rb1 = *reinterpret_cast<const i32x4*>(Bg1 + k0 + BK);
        }
        bf16x8 af[4], bfr[4];
#pragma unroll
        for (int m = 0; m < 4; ++m)
            af[m] = *reinterpret_cast<const bf16x8*>(&Al[(wr * 64 + m * 16 + lane15) * LDT + lhi * 8]);
#pragma unroll
        for (int n = 0; n < 4; ++n)
            bfr[n] = *reinterpret_cast<const bf16x8*>(&Bl[(wc * 64 + n * 16 + lane15) * LDT + lhi * 8]);
#pragma unroll
        for (int m = 0; m < 4; ++m)
#pragma unroll
            for (int n = 0; n < 4; ++n)
                acc[m][n] = MFMA16(af[m], bfr[n], acc[m][n]);
    }

    // epilogue: bias + store. C/D layout: col=lane&15, row=(lane>>4)*4+j  [m89]
#pragma unroll
    for (int m = 0; m < 4; ++m) {
#pragma unroll
        for (int n = 0; n < 4; ++n) {
            int col = col0 + wc * 64 + n * 16 + lane15;
            float bs = bias[col];
#pragma unroll
            for (int j = 0; j < 4; ++j) {
                int row = row0 + wr * 64 + m * 16 + lhi * 4 + j;
                store_out(&C[(size_t)row * N + col], acc[m][n][j] + bs);
            }
        }
    }
}

// ---------------------------------------------------------------- flash attention (causal)
// qkv: [B*N, 3072] bf16 (RoPE already applied to q,k sections). out: [B*N, 1024] bf16
__global__ void attn_kernel(const bf16* __restrict__ qkv, bf16* __restrict__ outp)
{
    constexpr int LDK = 72;                       // 64 + 8 pad
    __shared__ __align__(16) bf16 Kl[64 * LDK];   // K tile  [kv][hd]
    __shared__ __align__(16) bf16 Vt[64 * LDK];   // V tile transposed [hd][kv]
    __shared__ __align__(16) bf16 Pl[64 * LDK];   // per-wave P rows [4*16][kv]

    const int bh = blockIdx.x;                    // 32
    const int b = bh >> 4, h = bh & 15;
    const int q0 = blockIdx.y * 64;
    const int tid = threadIdx.x;
    const int w = tid >> 6, l = tid & 63;
    const int lane15 = l & 15, lhi = l >> 4;

    const size_t RS = 3072;
    const bf16* base = qkv + (size_t)b * 2048 * RS;

    // Q fragments hoisted to registers: A-layout row=lane&15, k=(lane>>4)*8+j
    bf16x8 qf0, qf1;
    {
        const bf16* qr = base + (size_t)(q0 + w * 16 + lane15) * RS + h * 64 + lhi * 8;
        qf0 = *reinterpret_cast<const bf16x8*>(qr);
        qf1 = *reinterpret_cast<const bf16x8*>(qr + 32);
    }

    float m_run[4], l_run[4];
    f32x4 o_acc[4] = {};
#pragma unroll
    for (int j = 0; j < 4; ++j) { m_run[j] = -1e30f; l_run[j] = 0.f; }

    const int ntiles = q0 / 64 + 1;
    for (int t = 0; t < ntiles; ++t) {
        const int kv0 = t * 64;
        __syncthreads();
        // stage K [64][64] -> Kl padded
#pragma unroll
        for (int cc = 0; cc < 2; ++cc) {
            int c = tid + cc * 256;
            int r = c >> 3, c8 = (c & 7) * 8;
            i32x4 v = *reinterpret_cast<const i32x4*>(base + (size_t)(kv0 + r) * RS + 1024 + h * 64 + c8);
            *reinterpret_cast<i32x4*>(&Kl[r * LDK + c8]) = v;
        }
        // stage V transposed -> Vt[hd][kv]
#pragma unroll
        for (int cc = 0; cc < 2; ++cc) {
            int c = tid + cc * 256;
            int r = c >> 3, c8 = (c & 7) * 8;
            i32x4 v = *reinterpret_cast<const i32x4*>(base + (size_t)(kv0 + r) * RS + 2048 + h * 64 + c8);
            const bf16* pv = reinterpret_cast<const bf16*>(&v);
#pragma unroll
            for (int i = 0; i < 8; ++i) Vt[(c8 + i) * LDK + r] = pv[i];
        }
        __syncthreads();

        // S = Q @ K^T  (wave's 16 q-rows x 64 kv)
        f32x4 s[4] = {};
#pragma unroll
        for (int n = 0; n < 4; ++n) {
            bf16x8 kf0 = *reinterpret_cast<const bf16x8*>(&Kl[(n * 16 + lane15) * LDK + lhi * 8]);
            bf16x8 kf1 = *reinterpret_cast<const bf16x8*>(&Kl[(n * 16 + lane15) * LDK + 32 + lhi * 8]);
            s[n] = MFMA16(qf0, kf0, s[n]);
            s[n] = MFMA16(qf1, kf1, s[n]);
        }

        // scale + causal mask
        const int qrow = q0 + w * 16 + lhi * 4;
#pragma unroll
        for (int n = 0; n < 4; ++n) {
            const int kvc = kv0 + n * 16 + lane15;
#pragma unroll
            for (int j = 0; j < 4; ++j) {
                float v = s[n][j] * 0.125f;
                s[n][j] = (kvc > qrow + j) ? -1e30f : v;
            }
        }

        // online softmax (row = 16 lanes of the group; reduce over lane&15)
        float alpha[4];
#pragma unroll
        for (int j = 0; j < 4; ++j) {
            float rm = fmaxf(fmaxf(s[0][j], s[1][j]), fmaxf(s[2][j], s[3][j]));
            rm = fmaxf(rm, __shfl_xor(rm, 1));
            rm = fmaxf(rm, __shfl_xor(rm, 2));
            rm = fmaxf(rm, __shfl_xor(rm, 4));
            rm = fmaxf(rm, __shfl_xor(rm, 8));
            float mnew = fmaxf(m_run[j], rm);
            alpha[j] = __expf(m_run[j] - mnew);
            m_run[j] = mnew;
        }
        float rs[4] = {0.f, 0.f, 0.f, 0.f};
#pragma unroll
        for (int n = 0; n < 4; ++n)
#pragma unroll
            for (int j = 0; j < 4; ++j) {
                float p = __expf(s[n][j] - m_run[j]);
                s[n][j] = p;
                rs[j] += p;
            }
#pragma unroll
        for (int j = 0; j < 4; ++j) {
            float r = rs[j];
            r += __shfl_xor(r, 1);
            r += __shfl_xor(r, 2);
            r += __shfl_xor(r, 4);
            r += __shfl_xor(r, 8);
            l_run[j] = l_run[j] * alpha[j] + r;
            o_acc[0][j] *= alpha[j];
            o_acc[1][j] *= alpha[j];
            o_acc[2][j] *= alpha[j];
            o_acc[3][j] *= alpha[j];
        }

        // P (D-layout) -> per-wave LDS -> re-read in A-layout
        bf16* Pw = &Pl[w * 16 * LDK];
#pragma unroll
        for (int n = 0; n < 4; ++n)
#pragma unroll
            for (int j = 0; j < 4; ++j)
                Pw[(lhi * 4 + j) * LDK + n * 16 + lane15] = __float2bfloat16(s[n][j]);

        bf16x8 pa0 = *reinterpret_cast<const bf16x8*>(&Pw[lane15 * LDK + lhi * 8]);
        bf16x8 pa1 = *reinterpret_cast<const bf16x8*>(&Pw[lane15 * LDK + 32 + lhi * 8]);
#pragma unroll
        for (int t2 = 0; t2 < 4; ++t2) {
            bf16x8 vf0 = *reinterpret_cast<const bf16x8*>(&Vt[(t2 * 16 + lane15) * LDK + lhi * 8]);
            bf16x8 vf1 = *reinterpret_cast<const bf16x8*>(&Vt[(t2 * 16 + lane15) * LDK + 32 + lhi * 8]);
            o_acc[t2] = MFMA16(pa0, vf0, o_acc[t2]);
            o_acc[t2] = MFMA16(pa1, vf1, o_acc[t2]);
        }
    }

    // epilogue: normalize, store bf16 [B*N, 1024]
#pragma unroll
    for (int j = 0; j < 4; ++j) {
        float inv = 1.f / l_run[j];
        size_t row = (size_t)(b * 2048 + q0 + w * 16 + lhi * 4 + j);
#pragma unroll
        for (int t2 = 0; t2 < 4; ++t2)
            outp[row * 1024 + h * 64 + t2 * 16 + lane15] = __float2bfloat16(o_acc[t2][j] * inv);
    }
}

// ---------------------------------------------------------------- launch
extern "C" void kernel_launch(void* const* d_in, const int* in_sizes, int n_in,
                              void* d_out, int out_size, void* d_ws, size_t ws_size,
                              hipStream_t stream)
{
    const float* x      = (const float*)d_in[0];
    const float* qkv_w  = (const float*)d_in[1];
    const float* qkv_b  = (const float*)d_in[2];
    const float* proj_w = (const float*)d_in[3];
    const float* proj_b = (const float*)d_in[4];
    float* out = (float*)d_out;

    char* ws = (char*)d_ws;
    bf16* x_bf   = (bf16*)ws;  ws += (size_t)4096 * 1024 * 2;
    bf16* wq_bf  = (bf16*)ws;  ws += (size_t)3072 * 1024 * 2;
    bf16* wp_bf  = (bf16*)ws;  ws += (size_t)1024 * 1024 * 2;
    bf16* qkvbuf = (bf16*)ws;  ws += (size_t)4096 * 3072 * 2;
    bf16* aout   = (bf16*)ws;  ws += (size_t)4096 * 1024 * 2;
    float2* tab  = (float2*)ws;

    cvt_f32_bf16<<<4096, 256, 0, stream>>>(x, x_bf, 1048576);
    cvt_f32_bf16<<<3072, 256, 0, stream>>>(qkv_w, wq_bf, 786432);
    cvt_f32_bf16<<<1024, 256, 0, stream>>>(proj_w, wp_bf, 262144);
    rope_table_kernel<<<256, 256, 0, stream>>>(tab);

    // qkv = x @ qkv_w.T + qkv_b   [4096, 3072] bf16
    gemm_bt_kernel<bf16><<<dim3(32, 24), 256, 0, stream>>>(x_bf, wq_bf, qkv_b, qkvbuf, 4096, 3072, 1024);
    // RoPE in place on q,k sections
    rope_apply_kernel<<<4096, 256, 0, stream>>>(qkvbuf, tab);
    // causal flash attention -> aout [4096, 1024] bf16
    attn_kernel<<<dim3(32, 32), 256, 0, stream>>>(qkvbuf, aout);
    // out = aout @ proj_w.T + proj_b  (fp32)
    gemm_bt_kernel<float><<<dim3(32, 8), 256, 0, stream>>>(aout, wp_bf, proj_b, out, 4096, 1024, 1024);
}

// Round 4
// 220.503 us; speedup vs baseline: 1.2157x; 1.2157x over previous
//
#include <hip/hip_runtime.h>
#include <hip/hip_bf16.h>
#include <cstdint>
#include <cstddef>

typedef __hip_bfloat16 bf16;
typedef short bf16x8 __attribute__((ext_vector_type(8)));
typedef float f32x4 __attribute__((ext_vector_type(4)));
typedef int i32x4 __attribute__((ext_vector_type(4)));

#define MFMA16(a, b, c) __builtin_amdgcn_mfma_f32_16x16x32_bf16((a), (b), (c), 0, 0, 0)

// async global->LDS, 16B per lane. dst must be wave-uniform base; HW adds lane*16.
__device__ __forceinline__ void glds16(const bf16* g, bf16* l)
{
    __builtin_amdgcn_global_load_lds(
        (const __attribute__((address_space(1))) void*)g,
        (__attribute__((address_space(3))) void*)l, 16, 0, 0);
}

// ---------------------------------------------------------------- converts
__global__ void cvt_f32_bf16(const float* __restrict__ in, bf16* __restrict__ out, int n4)
{
    int i = blockIdx.x * blockDim.x + threadIdx.x;
    if (i >= n4) return;
    float4 v = *reinterpret_cast<const float4*>(in + (size_t)i * 4);
    __align__(8) bf16 tmp[4];
    tmp[0] = __float2bfloat16(v.x);
    tmp[1] = __float2bfloat16(v.y);
    tmp[2] = __float2bfloat16(v.z);
    tmp[3] = __float2bfloat16(v.w);
    *reinterpret_cast<short4*>(out + (size_t)i * 4) = *reinterpret_cast<short4*>(tmp);
}

// ---------------------------------------------------------------- rope table
__global__ void rope_table_kernel(float2* __restrict__ tab)
{
    int i = blockIdx.x * blockDim.x + threadIdx.x;   // 65536
    int pos = i >> 5, f = i & 31;
    float inv = powf(10000.f, -(float)f * (1.f / 32.f));
    float ang = (float)pos * inv;
    tab[i] = make_float2(cosf(ang), sinf(ang));
}

// ---------------------------------------------------------------- rope apply (in-place on q,k cols of qkv buffer)
__global__ void rope_apply_kernel(bf16* __restrict__ qkv, const float2* __restrict__ tab)
{
    int idx = blockIdx.x * blockDim.x + threadIdx.x;   // 1,048,576 total; 8 bf16 each
    int row = idx >> 8;
    int cc  = (idx & 255) * 8;
    int pos = row & 2047;
    int hd  = cc & 63;
    bf16* p = qkv + (size_t)row * 3072 + cc;
    i32x4 v = *reinterpret_cast<const i32x4*>(p);
    bf16* e = reinterpret_cast<bf16*>(&v);
    const float2* tb = tab + pos * 32 + (hd >> 1);
#pragma unroll
    for (int pp = 0; pp < 4; ++pp) {
        float2 cs = tb[pp];
        float x1 = __bfloat162float(e[2 * pp]);
        float x2 = __bfloat162float(e[2 * pp + 1]);
        e[2 * pp]     = __float2bfloat16(x1 * cs.x - x2 * cs.y);
        e[2 * pp + 1] = __float2bfloat16(x2 * cs.x + x1 * cs.y);
    }
    *reinterpret_cast<i32x4*>(p) = v;
}

// ---------------------------------------------------------------- GEMM  C[M,N] = A[M,K] @ BT[N,K]^T + bias
// m97 structure: 128x128 tile, BK=32, linear LDS, global_load_lds width-16 staging.
__device__ inline void store_out(float* p, float v) { *p = v; }
__device__ inline void store_out(bf16* p, float v) { *p = __float2bfloat16(v); }

template <typename OutT>
__global__ void gemm_bt_kernel(const bf16* __restrict__ A, const bf16* __restrict__ BT,
                               const float* __restrict__ bias, OutT* __restrict__ C,
                               int M, int N, int K)
{
    constexpr int BM = 128, BN = 128, BK = 32;
    __shared__ __align__(16) bf16 Al[BM * BK];      // linear [row][32]
    __shared__ __align__(16) bf16 Bl[BN * BK];

    const int tid = threadIdx.x;
    const int l = tid & 63;
    const int w = tid >> 6;
    const int wr = w >> 1, wc = w & 1;              // 2x2 wave grid, 64x64 per wave
    const int l15 = l & 15, lhi = l >> 4;
    const int row0 = blockIdx.x * BM, col0 = blockIdx.y * BN;

    // staging: chunk g = c*256 + tid; row = g>>2, col8 = (g&3)*8; lds elem = g*8
    const int ar0 = tid >> 2, ar1 = (tid + 256) >> 2;
    const int ac  = (tid & 3) * 8;
    const bf16* Ag0 = A + (size_t)(row0 + ar0) * K + ac;
    const bf16* Ag1 = A + (size_t)(row0 + ar1) * K + ac;
    const bf16* Bg0 = BT + (size_t)(col0 + ar0) * K + ac;
    const bf16* Bg1 = BT + (size_t)(col0 + ar1) * K + ac;
    const int wbase = (tid & 192) * 8;              // wave-uniform LDS base (elems)
    bf16* sA0 = &Al[wbase];
    bf16* sA1 = &Al[2048 + wbase];
    bf16* sB0 = &Bl[wbase];
    bf16* sB1 = &Bl[2048 + wbase];

    f32x4 acc[4][4] = {};

    for (int k0 = 0; k0 < K; k0 += BK) {
        __syncthreads();                            // frag reads of prev tile done
        glds16(Ag0 + k0, sA0);
        glds16(Ag1 + k0, sA1);
        glds16(Bg0 + k0, sB0);
        glds16(Bg1 + k0, sB1);
        __syncthreads();                            // barrier drains vmcnt -> LDS visible
        bf16x8 af[4], bfr[4];
#pragma unroll
        for (int m = 0; m < 4; ++m)
            af[m] = *reinterpret_cast<const bf16x8*>(&Al[(wr * 64 + m * 16 + l15) * BK + lhi * 8]);
#pragma unroll
        for (int n = 0; n < 4; ++n)
            bfr[n] = *reinterpret_cast<const bf16x8*>(&Bl[(wc * 64 + n * 16 + l15) * BK + lhi * 8]);
#pragma unroll
        for (int m = 0; m < 4; ++m)
#pragma unroll
            for (int n = 0; n < 4; ++n)
                acc[m][n] = MFMA16(af[m], bfr[n], acc[m][n]);
    }

    // epilogue: bias + store. C/D layout: col=lane&15, row=(lane>>4)*4+j  [m89]
#pragma unroll
    for (int m = 0; m < 4; ++m) {
#pragma unroll
        for (int n = 0; n < 4; ++n) {
            int col = col0 + wc * 64 + n * 16 + l15;
            float bs = bias[col];
#pragma unroll
            for (int j = 0; j < 4; ++j) {
                int row = row0 + wr * 64 + m * 16 + lhi * 4 + j;
                store_out(&C[(size_t)row * N + col], acc[m][n][j] + bs);
            }
        }
    }
}

// ---------------------------------------------------------------- flash attention (causal)
// qkv: [B*N, 3072] bf16 (RoPE applied to q,k). out: [B*N, 1024] bf16
__global__ void attn_kernel(const bf16* __restrict__ qkv, bf16* __restrict__ outp)
{
    constexpr int LDK = 72;                       // 64 + 8 pad
    __shared__ __align__(16) bf16 Kl[64 * LDK];   // K tile  [kv][hd]
    __shared__ __align__(16) bf16 Vt[64 * LDK];   // V tile transposed [hd][kv]
    __shared__ __align__(16) bf16 Pl[64 * LDK];   // per-wave P rows [4*16][kv]

    const int bh = blockIdx.x;                    // 32
    const int b = bh >> 4, h = bh & 15;
    const int q0 = (31 - blockIdx.y) * 64;        // LPT: heaviest q-tiles dispatched first
    const int tid = threadIdx.x;
    const int w = tid >> 6, l = tid & 63;
    const int lane15 = l & 15, lhi = l >> 4;

    const size_t RS = 3072;
    const bf16* base = qkv + (size_t)b * 2048 * RS;

    // Q fragments hoisted: A-layout row=lane&15, k=(lane>>4)*8+j
    bf16x8 qf0, qf1;
    {
        const bf16* qr = base + (size_t)(q0 + w * 16 + lane15) * RS + h * 64 + lhi * 8;
        qf0 = *reinterpret_cast<const bf16x8*>(qr);
        qf1 = *reinterpret_cast<const bf16x8*>(qr + 32);
    }

    float m_run[4], l_run[4];
    f32x4 o_acc[4] = {};
#pragma unroll
    for (int j = 0; j < 4; ++j) { m_run[j] = -1e30f; l_run[j] = 0.f; }

    const int ntiles = q0 / 64 + 1;
    for (int t = 0; t < ntiles; ++t) {
        const int kv0 = t * 64;
        __syncthreads();
        // stage K [64][64] -> Kl padded (vector both sides)
#pragma unroll
        for (int cc = 0; cc < 2; ++cc) {
            int c = tid + cc * 256;
            int r = c >> 3, c8 = (c & 7) * 8;
            i32x4 v = *reinterpret_cast<const i32x4*>(base + (size_t)(kv0 + r) * RS + 1024 + h * 64 + c8);
            *reinterpret_cast<i32x4*>(&Kl[r * LDK + c8]) = v;
        }
        // stage V transposed: thread owns one hd column x 16 kv rows.
        // Global: instr j reads 64 contiguous bf16 across lanes (coalesced, L2-hot).
        // LDS: two b128 writes (conflict-floor) instead of 8 scalar 8-way writes.
        {
            const int hd = l;                      // lane = hd column
            const int seg = w;                     // wave = 16-kv segment
            const bf16* vcol = base + (size_t)(kv0 + seg * 16) * RS + 2048 + h * 64 + hd;
            __align__(16) bf16 tmp[16];
#pragma unroll
            for (int j = 0; j < 16; ++j) tmp[j] = vcol[(size_t)j * RS];
            *reinterpret_cast<i32x4*>(&Vt[hd * LDK + seg * 16])     = *reinterpret_cast<const i32x4*>(&tmp[0]);
            *reinterpret_cast<i32x4*>(&Vt[hd * LDK + seg * 16 + 8]) = *reinterpret_cast<const i32x4*>(&tmp[8]);
        }
        __syncthreads();

        // S = Q @ K^T  (wave's 16 q-rows x 64 kv)
        f32x4 s[4] = {};
#pragma unroll
        for (int n = 0; n < 4; ++n) {
            bf16x8 kf0 = *reinterpret_cast<const bf16x8*>(&Kl[(n * 16 + lane15) * LDK + lhi * 8]);
            bf16x8 kf1 = *reinterpret_cast<const bf16x8*>(&Kl[(n * 16 + lane15) * LDK + 32 + lhi * 8]);
            s[n] = MFMA16(qf0, kf0, s[n]);
            s[n] = MFMA16(qf1, kf1, s[n]);
        }

        // scale + causal mask
        const int qrow = q0 + w * 16 + lhi * 4;
#pragma unroll
        for (int n = 0; n < 4; ++n) {
            const int kvc = kv0 + n * 16 + lane15;
#pragma unroll
            for (int j = 0; j < 4; ++j) {
                float v = s[n][j] * 0.125f;
                s[n][j] = (kvc > qrow + j) ? -1e30f : v;
            }
        }

        // online softmax (reduce over lane&15 group)
        float alpha[4];
#pragma unroll
        for (int j = 0; j < 4; ++j) {
            float rm = fmaxf(fmaxf(s[0][j], s[1][j]), fmaxf(s[2][j], s[3][j]));
            rm = fmaxf(rm, __shfl_xor(rm, 1));
            rm = fmaxf(rm, __shfl_xor(rm, 2));
            rm = fmaxf(rm, __shfl_xor(rm, 4));
            rm = fmaxf(rm, __shfl_xor(rm, 8));
            float mnew = fmaxf(m_run[j], rm);
            alpha[j] = __expf(m_run[j] - mnew);
            m_run[j] = mnew;
        }
        float rs[4] = {0.f, 0.f, 0.f, 0.f};
#pragma unroll
        for (int n = 0; n < 4; ++n)
#pragma unroll
            for (int j = 0; j < 4; ++j) {
                float p = __expf(s[n][j] - m_run[j]);
                s[n][j] = p;
                rs[j] += p;
            }
#pragma unroll
        for (int j = 0; j < 4; ++j) {
            float r = rs[j];
            r += __shfl_xor(r, 1);
            r += __shfl_xor(r, 2);
            r += __shfl_xor(r, 4);
            r += __shfl_xor(r, 8);
            l_run[j] = l_run[j] * alpha[j] + r;
            o_acc[0][j] *= alpha[j];
            o_acc[1][j] *= alpha[j];
            o_acc[2][j] *= alpha[j];
            o_acc[3][j] *= alpha[j];
        }

        // P (D-layout) -> per-wave LDS -> re-read in A-layout
        bf16* Pw = &Pl[w * 16 * LDK];
#pragma unroll
        for (int n = 0; n < 4; ++n)
#pragma unroll
            for (int j = 0; j < 4; ++j)
                Pw[(lhi * 4 + j) * LDK + n * 16 + lane15] = __float2bfloat16(s[n][j]);

        bf16x8 pa0 = *reinterpret_cast<const bf16x8*>(&Pw[lane15 * LDK + lhi * 8]);
        bf16x8 pa1 = *reinterpret_cast<const bf16x8*>(&Pw[lane15 * LDK + 32 + lhi * 8]);
#pragma unroll
        for (int t2 = 0; t2 < 4; ++t2) {
            bf16x8 vf0 = *reinterpret_cast<const bf16x8*>(&Vt[(t2 * 16 + lane15) * LDK + lhi * 8]);
            bf16x8 vf1 = *reinterpret_cast<const bf16x8*>(&Vt[(t2 * 16 + lane15) * LDK + 32 + lhi * 8]);
            o_acc[t2] = MFMA16(pa0, vf0, o_acc[t2]);
            o_acc[t2] = MFMA16(pa1, vf1, o_acc[t2]);
        }
    }

    // epilogue: normalize, store bf16 [B*N, 1024]
#pragma unroll
    for (int j = 0; j < 4; ++j) {
        float inv = 1.f / l_run[j];
        size_t row = (size_t)(b * 2048 + q0 + w * 16 + lhi * 4 + j);
#pragma unroll
        for (int t2 = 0; t2 < 4; ++t2)
            outp[row * 1024 + h * 64 + t2 * 16 + lane15] = __float2bfloat16(o_acc[t2][j] * inv);
    }
}

// ---------------------------------------------------------------- launch
extern "C" void kernel_launch(void* const* d_in, const int* in_sizes, int n_in,
                              void* d_out, int out_size, void* d_ws, size_t ws_size,
                              hipStream_t stream)
{
    const float* x      = (const float*)d_in[0];
    const float* qkv_w  = (const float*)d_in[1];
    const float* qkv_b  = (const float*)d_in[2];
    const float* proj_w = (const float*)d_in[3];
    const float* proj_b = (const float*)d_in[4];
    float* out = (float*)d_out;

    char* ws = (char*)d_ws;
    bf16* x_bf   = (bf16*)ws;  ws += (size_t)4096 * 1024 * 2;
    bf16* wq_bf  = (bf16*)ws;  ws += (size_t)3072 * 1024 * 2;
    bf16* wp_bf  = (bf16*)ws;  ws += (size_t)1024 * 1024 * 2;
    bf16* qkvbuf = (bf16*)ws;  ws += (size_t)4096 * 3072 * 2;
    bf16* aout   = (bf16*)ws;  ws += (size_t)4096 * 1024 * 2;
    float2* tab  = (float2*)ws;

    cvt_f32_bf16<<<4096, 256, 0, stream>>>(x, x_bf, 1048576);
    cvt_f32_bf16<<<3072, 256, 0, stream>>>(qkv_w, wq_bf, 786432);
    cvt_f32_bf16<<<1024, 256, 0, stream>>>(proj_w, wp_bf, 262144);
    rope_table_kernel<<<256, 256, 0, stream>>>(tab);

    // qkv = x @ qkv_w.T + qkv_b   [4096, 3072] bf16
    gemm_bt_kernel<bf16><<<dim3(32, 24), 256, 0, stream>>>(x_bf, wq_bf, qkv_b, qkvbuf, 4096, 3072, 1024);
    // RoPE in place on q,k sections
    rope_apply_kernel<<<4096, 256, 0, stream>>>(qkvbuf, tab);
    // causal flash attention -> aout [4096, 1024] bf16
    attn_kernel<<<dim3(32, 32), 256, 0, stream>>>(qkvbuf, aout);
    // out = aout @ proj_w.T + proj_b  (fp32)
    gemm_bt_kernel<float><<<dim3(32, 8), 256, 0, stream>>>(aout, wp_bf, proj_b, out, 4096, 1024, 1024);
}

// Round 5
// 218.553 us; speedup vs baseline: 1.2266x; 1.0089x over previous
//
#include <hip/hip_runtime.h>
#include <hip/hip_bf16.h>
#include <cstdint>
#include <cstddef>

typedef __hip_bfloat16 bf16;
typedef short bf16x8 __attribute__((ext_vector_type(8)));
typedef float f32x4 __attribute__((ext_vector_type(4)));
typedef int i32x4 __attribute__((ext_vector_type(4)));

#define MFMA16(a, b, c) __builtin_amdgcn_mfma_f32_16x16x32_bf16((a), (b), (c), 0, 0, 0)

// async global->LDS, 16B per lane. dst must be wave-uniform base; HW adds lane*16.
__device__ __forceinline__ void glds16(const bf16* g, bf16* l)
{
    __builtin_amdgcn_global_load_lds(
        (const __attribute__((address_space(1))) void*)g,
        (__attribute__((address_space(3))) void*)l, 16, 0, 0);
}

// ---------------------------------------------------------------- converts
__global__ void cvt_f32_bf16(const float* __restrict__ in, bf16* __restrict__ out, int n4)
{
    int i = blockIdx.x * blockDim.x + threadIdx.x;
    if (i >= n4) return;
    float4 v = *reinterpret_cast<const float4*>(in + (size_t)i * 4);
    __align__(8) bf16 tmp[4];
    tmp[0] = __float2bfloat16(v.x);
    tmp[1] = __float2bfloat16(v.y);
    tmp[2] = __float2bfloat16(v.z);
    tmp[3] = __float2bfloat16(v.w);
    *reinterpret_cast<short4*>(out + (size_t)i * 4) = *reinterpret_cast<short4*>(tmp);
}

// ---------------------------------------------------------------- rope table
__global__ void rope_table_kernel(float2* __restrict__ tab)
{
    int i = blockIdx.x * blockDim.x + threadIdx.x;   // 65536
    int pos = i >> 5, f = i & 31;
    float inv = powf(10000.f, -(float)f * (1.f / 32.f));
    float ang = (float)pos * inv;
    tab[i] = make_float2(cosf(ang), sinf(ang));
}

// ---------------------------------------------------------------- rope apply (in-place on q,k cols of qkv buffer)
__global__ void rope_apply_kernel(bf16* __restrict__ qkv, const float2* __restrict__ tab)
{
    int idx = blockIdx.x * blockDim.x + threadIdx.x;   // 1,048,576 total; 8 bf16 each
    int row = idx >> 8;
    int cc  = (idx & 255) * 8;
    int pos = row & 2047;
    int hd  = cc & 63;
    bf16* p = qkv + (size_t)row * 3072 + cc;
    i32x4 v = *reinterpret_cast<const i32x4*>(p);
    bf16* e = reinterpret_cast<bf16*>(&v);
    const float2* tb = tab + pos * 32 + (hd >> 1);
#pragma unroll
    for (int pp = 0; pp < 4; ++pp) {
        float2 cs = tb[pp];
        float x1 = __bfloat162float(e[2 * pp]);
        float x2 = __bfloat162float(e[2 * pp + 1]);
        e[2 * pp]     = __float2bfloat16(x1 * cs.x - x2 * cs.y);
        e[2 * pp + 1] = __float2bfloat16(x2 * cs.x + x1 * cs.y);
    }
    *reinterpret_cast<i32x4*>(p) = v;
}

// ---------------------------------------------------------------- GEMM  C[M,N] = A[M,K] @ BT[N,K]^T + bias
// m97 structure: 128x128 tile, BK=32, linear LDS, global_load_lds width-16 staging.
__device__ inline void store_out(float* p, float v) { *p = v; }
__device__ inline void store_out(bf16* p, float v) { *p = __float2bfloat16(v); }

template <typename OutT>
__global__ void gemm_bt_kernel(const bf16* __restrict__ A, const bf16* __restrict__ BT,
                               const float* __restrict__ bias, OutT* __restrict__ C,
                               int M, int N, int K)
{
    constexpr int BM = 128, BN = 128, BK = 32;
    __shared__ __align__(16) bf16 Al[BM * BK];      // linear [row][32]
    __shared__ __align__(16) bf16 Bl[BN * BK];

    const int tid = threadIdx.x;
    const int l = tid & 63;
    const int w = tid >> 6;
    const int wr = w >> 1, wc = w & 1;              // 2x2 wave grid, 64x64 per wave
    const int l15 = l & 15, lhi = l >> 4;
    const int row0 = blockIdx.x * BM, col0 = blockIdx.y * BN;

    const int ar0 = tid >> 2, ar1 = (tid + 256) >> 2;
    const int ac  = (tid & 3) * 8;
    const bf16* Ag0 = A + (size_t)(row0 + ar0) * K + ac;
    const bf16* Ag1 = A + (size_t)(row0 + ar1) * K + ac;
    const bf16* Bg0 = BT + (size_t)(col0 + ar0) * K + ac;
    const bf16* Bg1 = BT + (size_t)(col0 + ar1) * K + ac;
    const int wbase = (tid & 192) * 8;              // wave-uniform LDS base (elems)
    bf16* sA0 = &Al[wbase];
    bf16* sA1 = &Al[2048 + wbase];
    bf16* sB0 = &Bl[wbase];
    bf16* sB1 = &Bl[2048 + wbase];

    f32x4 acc[4][4] = {};

    for (int k0 = 0; k0 < K; k0 += BK) {
        __syncthreads();                            // frag reads of prev tile done
        glds16(Ag0 + k0, sA0);
        glds16(Ag1 + k0, sA1);
        glds16(Bg0 + k0, sB0);
        glds16(Bg1 + k0, sB1);
        __syncthreads();                            // barrier drains vmcnt -> LDS visible
        bf16x8 af[4], bfr[4];
#pragma unroll
        for (int m = 0; m < 4; ++m)
            af[m] = *reinterpret_cast<const bf16x8*>(&Al[(wr * 64 + m * 16 + l15) * BK + lhi * 8]);
#pragma unroll
        for (int n = 0; n < 4; ++n)
            bfr[n] = *reinterpret_cast<const bf16x8*>(&Bl[(wc * 64 + n * 16 + l15) * BK + lhi * 8]);
#pragma unroll
        for (int m = 0; m < 4; ++m)
#pragma unroll
            for (int n = 0; n < 4; ++n)
                acc[m][n] = MFMA16(af[m], bfr[n], acc[m][n]);
    }

    // epilogue: bias + store. C/D layout: col=lane&15, row=(lane>>4)*4+j  [m89]
#pragma unroll
    for (int m = 0; m < 4; ++m) {
#pragma unroll
        for (int n = 0; n < 4; ++n) {
            int col = col0 + wc * 64 + n * 16 + l15;
            float bs = bias[col];
#pragma unroll
            for (int j = 0; j < 4; ++j) {
                int row = row0 + wr * 64 + m * 16 + lhi * 4 + j;
                store_out(&C[(size_t)row * N + col], acc[m][n][j] + bs);
            }
        }
    }
}

// ---------------------------------------------------------------- flash attention (causal)
// qkv: [B*N, 3072] bf16 (RoPE applied to q,k). out: [B*N, 1024] bf16
// Double-buffered K/V with T14 async-stage split: issue loads for t+1 before
// computing t; write regs->LDS[nxt] after compute; ONE barrier per iteration
// (writers of buf[nxt] are past the previous barrier, so all readers of
// buf[nxt]'s old contents have finished).
__global__ void attn_kernel(const bf16* __restrict__ qkv, bf16* __restrict__ outp)
{
    constexpr int LDK = 72;                         // 64 + 8 pad
    __shared__ __align__(16) bf16 Kl[2][64 * LDK];  // K tiles [kv][hd]
    __shared__ __align__(16) bf16 Vt[2][64 * LDK];  // V tiles transposed [hd][kv]
    __shared__ __align__(16) bf16 Pl[64 * LDK];     // per-wave P rows

    const int bh = blockIdx.x;                      // 32
    const int b = bh >> 4, h = bh & 15;
    const int q0 = (31 - blockIdx.y) * 64;          // LPT: heaviest q-tiles first
    const int tid = threadIdx.x;
    const int w = tid >> 6, l = tid & 63;
    const int l15 = l & 15, lhi = l >> 4;

    const size_t RS = 3072;
    const bf16* base = qkv + (size_t)b * 2048 * RS;

    // Q fragments hoisted: A-layout row=lane&15, k=(lane>>4)*8+j
    bf16x8 qf0, qf1;
    {
        const bf16* qr = base + (size_t)(q0 + w * 16 + l15) * RS + h * 64 + lhi * 8;
        qf0 = *reinterpret_cast<const bf16x8*>(qr);
        qf1 = *reinterpret_cast<const bf16x8*>(qr + 32);
    }

    // staging geometry
    const int kr  = tid >> 3;                       // K: rows 0..31 (+32 for 2nd)
    const int kc8 = (tid & 7) * 8;
    const bf16* kp = base + (size_t)kr * RS + 1024 + h * 64 + kc8;
    const bf16* vp = base + (size_t)(w * 16) * RS + 2048 + h * 64 + l;  // V col = lane

    i32x4 ka, kb;
    __align__(16) bf16 vt16[16];

    // ---- prologue: load + write tile 0
    ka = *reinterpret_cast<const i32x4*>(kp);
    kb = *reinterpret_cast<const i32x4*>(kp + 32 * RS);
#pragma unroll
    for (int j = 0; j < 16; ++j) vt16[j] = vp[(size_t)j * RS];
    *reinterpret_cast<i32x4*>(&Kl[0][kr * LDK + kc8])        = ka;
    *reinterpret_cast<i32x4*>(&Kl[0][(kr + 32) * LDK + kc8]) = kb;
    *reinterpret_cast<i32x4*>(&Vt[0][l * LDK + w * 16])      = *reinterpret_cast<const i32x4*>(&vt16[0]);
    *reinterpret_cast<i32x4*>(&Vt[0][l * LDK + w * 16 + 8])  = *reinterpret_cast<const i32x4*>(&vt16[8]);
    __syncthreads();

    float m_run[4], l_run[4];
    f32x4 o_acc[4] = {};
#pragma unroll
    for (int j = 0; j < 4; ++j) { m_run[j] = -1e30f; l_run[j] = 0.f; }

    const int ntiles = q0 / 64 + 1;
    int cur = 0;
    for (int t = 0; t < ntiles; ++t) {
        const int kv0 = t * 64;
        const bool pf = (t + 1 < ntiles);
        if (pf) {                                   // issue next-tile loads NOW (hide under compute)
            kp += 64 * RS;
            vp += 64 * RS;
            ka = *reinterpret_cast<const i32x4*>(kp);
            kb = *reinterpret_cast<const i32x4*>(kp + 32 * RS);
#pragma unroll
            for (int j = 0; j < 16; ++j) vt16[j] = vp[(size_t)j * RS];
        }

        const bf16* Kc = &Kl[cur][0];
        const bf16* Vc = &Vt[cur][0];

        // S = Q @ K^T  (wave's 16 q-rows x 64 kv)
        f32x4 s[4] = {};
#pragma unroll
        for (int n = 0; n < 4; ++n) {
            bf16x8 kf0 = *reinterpret_cast<const bf16x8*>(&Kc[(n * 16 + l15) * LDK + lhi * 8]);
            bf16x8 kf1 = *reinterpret_cast<const bf16x8*>(&Kc[(n * 16 + l15) * LDK + 32 + lhi * 8]);
            s[n] = MFMA16(qf0, kf0, s[n]);
            s[n] = MFMA16(qf1, kf1, s[n]);
        }

        // scale + causal mask
        const int qrow = q0 + w * 16 + lhi * 4;
#pragma unroll
        for (int n = 0; n < 4; ++n) {
            const int kvc = kv0 + n * 16 + l15;
#pragma unroll
            for (int j = 0; j < 4; ++j) {
                float v = s[n][j] * 0.125f;
                s[n][j] = (kvc > qrow + j) ? -1e30f : v;
            }
        }

        // online softmax (reduce over lane&15 group)
        float alpha[4];
#pragma unroll
        for (int j = 0; j < 4; ++j) {
            float rm = fmaxf(fmaxf(s[0][j], s[1][j]), fmaxf(s[2][j], s[3][j]));
            rm = fmaxf(rm, __shfl_xor(rm, 1));
            rm = fmaxf(rm, __shfl_xor(rm, 2));
            rm = fmaxf(rm, __shfl_xor(rm, 4));
            rm = fmaxf(rm, __shfl_xor(rm, 8));
            float mnew = fmaxf(m_run[j], rm);
            alpha[j] = __expf(m_run[j] - mnew);
            m_run[j] = mnew;
        }
        float rs[4] = {0.f, 0.f, 0.f, 0.f};
#pragma unroll
        for (int n = 0; n < 4; ++n)
#pragma unroll
            for (int j = 0; j < 4; ++j) {
                float p = __expf(s[n][j] - m_run[j]);
                s[n][j] = p;
                rs[j] += p;
            }
#pragma unroll
        for (int j = 0; j < 4; ++j) {
            float r = rs[j];
            r += __shfl_xor(r, 1);
            r += __shfl_xor(r, 2);
            r += __shfl_xor(r, 4);
            r += __shfl_xor(r, 8);
            l_run[j] = l_run[j] * alpha[j] + r;
            o_acc[0][j] *= alpha[j];
            o_acc[1][j] *= alpha[j];
            o_acc[2][j] *= alpha[j];
            o_acc[3][j] *= alpha[j];
        }

        // P (D-layout) -> per-wave LDS -> re-read in A-layout (wave-local, no barrier)
        bf16* Pw = &Pl[w * 16 * LDK];
#pragma unroll
        for (int n = 0; n < 4; ++n)
#pragma unroll
            for (int j = 0; j < 4; ++j)
                Pw[(lhi * 4 + j) * LDK + n * 16 + l15] = __float2bfloat16(s[n][j]);

        bf16x8 pa0 = *reinterpret_cast<const bf16x8*>(&Pw[l15 * LDK + lhi * 8]);
        bf16x8 pa1 = *reinterpret_cast<const bf16x8*>(&Pw[l15 * LDK + 32 + lhi * 8]);
#pragma unroll
        for (int t2 = 0; t2 < 4; ++t2) {
            bf16x8 vf0 = *reinterpret_cast<const bf16x8*>(&Vc[(t2 * 16 + l15) * LDK + lhi * 8]);
            bf16x8 vf1 = *reinterpret_cast<const bf16x8*>(&Vc[(t2 * 16 + l15) * LDK + 32 + lhi * 8]);
            o_acc[t2] = MFMA16(pa0, vf0, o_acc[t2]);
            o_acc[t2] = MFMA16(pa1, vf1, o_acc[t2]);
        }

        if (pf) {                                   // drain loads, write nxt buffer, single barrier
            const int nxt = cur ^ 1;
            *reinterpret_cast<i32x4*>(&Kl[nxt][kr * LDK + kc8])        = ka;
            *reinterpret_cast<i32x4*>(&Kl[nxt][(kr + 32) * LDK + kc8]) = kb;
            *reinterpret_cast<i32x4*>(&Vt[nxt][l * LDK + w * 16])      = *reinterpret_cast<const i32x4*>(&vt16[0]);
            *reinterpret_cast<i32x4*>(&Vt[nxt][l * LDK + w * 16 + 8])  = *reinterpret_cast<const i32x4*>(&vt16[8]);
            __syncthreads();
            cur = nxt;
        }
    }

    // epilogue: normalize, store bf16 [B*N, 1024]
#pragma unroll
    for (int j = 0; j < 4; ++j) {
        float inv = 1.f / l_run[j];
        size_t row = (size_t)(b * 2048 + q0 + w * 16 + lhi * 4 + j);
#pragma unroll
        for (int t2 = 0; t2 < 4; ++t2)
            outp[row * 1024 + h * 64 + t2 * 16 + l15] = __float2bfloat16(o_acc[t2][j] * inv);
    }
}

// ---------------------------------------------------------------- launch
extern "C" void kernel_launch(void* const* d_in, const int* in_sizes, int n_in,
                              void* d_out, int out_size, void* d_ws, size_t ws_size,
                              hipStream_t stream)
{
    const float* x      = (const float*)d_in[0];
    const float* qkv_w  = (const float*)d_in[1];
    const float* qkv_b  = (const float*)d_in[2];
    const float* proj_w = (const float*)d_in[3];
    const float* proj_b = (const float*)d_in[4];
    float* out = (float*)d_out;

    char* ws = (char*)d_ws;
    bf16* x_bf   = (bf16*)ws;  ws += (size_t)4096 * 1024 * 2;
    bf16* wq_bf  = (bf16*)ws;  ws += (size_t)3072 * 1024 * 2;
    bf16* wp_bf  = (bf16*)ws;  ws += (size_t)1024 * 1024 * 2;
    bf16* qkvbuf = (bf16*)ws;  ws += (size_t)4096 * 3072 * 2;
    bf16* aout   = (bf16*)ws;  ws += (size_t)4096 * 1024 * 2;
    float2* tab  = (float2*)ws;

    cvt_f32_bf16<<<4096, 256, 0, stream>>>(x, x_bf, 1048576);
    cvt_f32_bf16<<<3072, 256, 0, stream>>>(qkv_w, wq_bf, 786432);
    cvt_f32_bf16<<<1024, 256, 0, stream>>>(proj_w, wp_bf, 262144);
    rope_table_kernel<<<256, 256, 0, stream>>>(tab);

    // qkv = x @ qkv_w.T + qkv_b   [4096, 3072] bf16
    gemm_bt_kernel<bf16><<<dim3(32, 24), 256, 0, stream>>>(x_bf, wq_bf, qkv_b, qkvbuf, 4096, 3072, 1024);
    // RoPE in place on q,k sections
    rope_apply_kernel<<<4096, 256, 0, stream>>>(qkvbuf, tab);
    // causal flash attention -> aout [4096, 1024] bf16
    attn_kernel<<<dim3(32, 32), 256, 0, stream>>>(qkvbuf, aout);
    // out = aout @ proj_w.T + proj_b  (fp32)
    gemm_bt_kernel<float><<<dim3(32, 8), 256, 0, stream>>>(aout, wp_bf, proj_b, out, 4096, 1024, 1024);
}